// Round 33
// baseline (104.783 us; speedup 1.0000x reference)
//
#include <hip/hip_runtime.h>
#include <math.h>

#define EMB 512
#define VQ 32
#define MCODES 32   // 2*LOG2
#define EPS 1e-8f

#define KSTEP 32                    // e-dims per K-step
#define NSTEPS 16
#define TILE 128                    // tokens per block
#define HSTRIDE 1040                // 8 tokens * 128B + 16B pad
#define HBUFSZ (16 * HSTRIDE)       // 16640 B
#define WBUFSZ 4096                 // 32 rows * 128B
#define HOFF0 0
#define HOFF1 HBUFSZ
#define WOFF0 (2 * HBUFSZ)
#define WOFF1 (2 * HBUFSZ + WBUFSZ)
#define LDS_TOTAL (2 * HBUFSZ + 2 * WBUFSZ)   // 41472 B

#define ACC4(A, V)                                                        \
    A.x += V.x * w0.x; A.x += V.y * w1.x; A.x += V.z * w2.x; A.x += V.w * w3.x; \
    A.y += V.x * w0.y; A.y += V.y * w1.y; A.y += V.z * w2.y; A.y += V.w * w3.y; \
    A.z += V.x * w0.z; A.z += V.y * w1.z; A.z += V.z * w2.z; A.z += V.w * w3.z; \
    A.w += V.x * w0.w; A.w += V.y * w1.w; A.w += V.z * w2.w; A.w += V.w * w3.w;

// ---------------------------------------------------------------------------
// prep: normalize codebook rows, G = 2*En, q = ||En||^2, C = En @ W_inv
// ---------------------------------------------------------------------------
__global__ __launch_bounds__(256)
void prep_kernel(const float* __restrict__ emb, const float* __restrict__ W_inv,
                 float* __restrict__ Cw, float* __restrict__ G, float* __restrict__ qv,
                 float* __restrict__ loss_out) {
  const int b = blockIdx.x;
  const int tid = threadIdx.x;
  __shared__ float En_s[VQ];
  float ss = 0.f;
#pragma unroll
  for (int d = 0; d < VQ; ++d) { float v = emb[b * VQ + d]; ss += v * v; }
  const float inv = 1.0f / (sqrtf(ss) + EPS);
  if (tid < VQ) En_s[tid] = emb[b * VQ + tid] * inv;
  __syncthreads();
  float a0 = 0.f, a1 = 0.f;
#pragma unroll 8
  for (int d = 0; d < VQ; ++d) {
    const float en = En_s[d];
    const float2 wv = ((const float2*)(W_inv + d * EMB))[tid];
    a0 += en * wv.x;
    a1 += en * wv.y;
  }
  ((float2*)(Cw + b * EMB))[tid] = make_float2(a0, a1);
  if (tid < VQ) G[b * VQ + tid] = 2.0f * En_s[tid];
  if (tid == 0) {
    float qq = 0.f;
#pragma unroll
    for (int d = 0; d < VQ; ++d) qq += En_s[d] * En_s[d];
    qv[b] = qq;
    if (b == 0) loss_out[0] = 0.0f;   // vq_loss
  }
}

// ---------------------------------------------------------------------------
// proj v9 — FINAL (session-best, reproduced 8x at 104-107us total):
// async-staged 2-phase (m97 pattern). Per K-step: stage(next buf) via 5
// async 1KB gload_lds per wave issued BEFORE compute, compute current buf
// from LDS, barrier. 128 tok/block, grid 512 (2 blocks/CU -> cross-block
// stage/compute overlap). Verified absmax 9.77e-4.
// ---------------------------------------------------------------------------
__global__ __launch_bounds__(256)
void proj_kernel(const float* __restrict__ h, const int* __restrict__ mask,
                 const float* __restrict__ W_proj, const float* __restrict__ b_proj,
                 const float* __restrict__ G, const float* __restrict__ qv,
                 float* __restrict__ Aout, float* __restrict__ code_out) {
  const int tid = threadIdx.x;
  const int w = tid >> 6;            // wave 0..3
  const int lane = tid & 63;
  const int dg = tid & 7;            // out-dims 4*dg..4*dg+3
  const int ts = tid >> 3;           // 0..31 : token-strip (4 tokens)
  const int tile = blockIdx.x * TILE;

  __shared__ __align__(16) char lds[LDS_TOTAL];

  const int hoff[2] = {HOFF0, HOFF1};
  const int woff[2] = {WOFF0, WOFF1};

  const int srow = lane >> 3;        // staging: row within 8-row call
  const int scol = (lane & 7) * 4;   // staging: float offset (16B granule)

  // ---- async stage of one K-step into buffer b (issue-only, no waits) ----
  auto stage = [&](int b, int s) {
#pragma unroll
    for (int i = 0; i < 4; ++i) {
      const int c = 4 * w + i;
      const float* g = h + (size_t)(tile + 8 * c + srow) * EMB + s * KSTEP + scol;
      char* l = &lds[hoff[b] + c * HSTRIDE];
      __builtin_amdgcn_global_load_lds((const __attribute__((address_space(1))) void*)g,
                                       (__attribute__((address_space(3))) void*)l, 16, 0, 0);
    }
    {
      const float* g = W_proj + (size_t)(s * KSTEP + 8 * w + srow) * VQ + scol;
      char* l = &lds[woff[b] + w * 1024];
      __builtin_amdgcn_global_load_lds((const __attribute__((address_space(1))) void*)g,
                                       (__attribute__((address_space(3))) void*)l, 16, 0, 0);
    }
  };

  float4 a0 = make_float4(0.f, 0.f, 0.f, 0.f), a1 = a0, a2 = a0, a3 = a0;
  const int hrowbase = (ts >> 1) * HSTRIDE + (ts & 1) * 512;

  stage(0, 0);
  __syncthreads();                   // buf0 ready

  int b = 0;
  for (int s = 0; s < NSTEPS; ++s) {
    if (s + 1 < NSTEPS) stage(b ^ 1, s + 1);    // issue-early
    const char* hb = &lds[hoff[b]];
    const char* wb = &lds[woff[b]];
#pragma unroll
    for (int kf = 0; kf < 8; ++kf) {            // 4 k-dims per kf
      const float4 w0 = *(const float4*)(wb + (4 * kf + 0) * 128 + dg * 16);
      const float4 w1 = *(const float4*)(wb + (4 * kf + 1) * 128 + dg * 16);
      const float4 w2 = *(const float4*)(wb + (4 * kf + 2) * 128 + dg * 16);
      const float4 w3 = *(const float4*)(wb + (4 * kf + 3) * 128 + dg * 16);
      const float4 v0 = *(const float4*)(hb + hrowbase + 0 * 128 + kf * 16);
      const float4 v1 = *(const float4*)(hb + hrowbase + 1 * 128 + kf * 16);
      const float4 v2 = *(const float4*)(hb + hrowbase + 2 * 128 + kf * 16);
      const float4 v3 = *(const float4*)(hb + hrowbase + 3 * 128 + kf * 16);
      ACC4(a0, v0) ACC4(a1, v1) ACC4(a2, v2) ACC4(a3, v3)
    }
    __syncthreads();                 // drains staged loads; protects buffer reuse
    b ^= 1;
  }

  // ---- epilogue (R9-proven): redistribute via LDS, norm/softmax/code ----
  float* part = (float*)lds;         // reuse as [128][36] floats (18432B)
  *(float4*)&part[(4 * ts + 0) * 36 + dg * 4] = a0;
  *(float4*)&part[(4 * ts + 1) * 36 + dg * 4] = a1;
  *(float4*)&part[(4 * ts + 2) * 36 + dg * 4] = a2;
  *(float4*)&part[(4 * ts + 3) * 36 + dg * 4] = a3;
  __syncthreads();

  if (tid < 128) {
    const int t = tile + tid;
    const float4* bp4 = (const float4*)b_proj;
    float4 hp[8];
    float ssum = 0.f;
#pragma unroll
    for (int k = 0; k < 8; ++k) {
      float4 v = *(const float4*)&part[tid * 36 + k * 4];
      const float4 bb = bp4[k];
      v.x += bb.x; v.y += bb.y; v.z += bb.z; v.w += bb.w;
      hp[k] = v;
      ssum += v.x * v.x + v.y * v.y + v.z * v.z + v.w * v.w;
    }
    const float inv = 1.0f / (sqrtf(ssum) + EPS);
#pragma unroll
    for (int k = 0; k < 8; ++k) {
      hp[k].x *= inv; hp[k].y *= inv; hp[k].z *= inv; hp[k].w *= inv;
    }
    const float4* G4 = (const float4*)G;   // [32][8] float4, rows = 2*En_m
    float av[32];
    int code = 0;
#pragma unroll
    for (int g = 0; g < 16; ++g) {
      float d0 = 0.f, d1 = 0.f;
#pragma unroll
      for (int k = 0; k < 8; ++k) {
        const float4 g0 = G4[(2 * g) * 8 + k];
        const float4 g1 = G4[(2 * g + 1) * 8 + k];
        const float4 hv = hp[k];
        d0 += hv.x * g0.x + hv.y * g0.y + hv.z * g0.z + hv.w * g0.w;
        d1 += hv.x * g1.x + hv.y * g1.y + hv.z * g1.z + hv.w * g1.w;
      }
      // s_m = 2*hn.En_m - ||En_m||^2 (||hn||^2 cancels inside the pair softmax)
      const float s0 = d0 - qv[2 * g];
      const float s1 = d1 - qv[2 * g + 1];
      const float mx = fmaxf(s0, s1);
      const float e0 = expf(s0 - mx);
      const float e1 = expf(s1 - mx);
      const float rs = 1.0f / (e0 + e1);
      av[2 * g] = e0 * rs;
      av[2 * g + 1] = e1 * rs;
      code |= (e1 > e0) ? (1 << g) : 0;   // argmax, first index wins ties
    }
    const int mk = mask[t];
    const float msk = (mk == 1) ? 1.0f : 0.0f;
    float4* Ao = (float4*)(Aout + (size_t)t * MCODES);
#pragma unroll
    for (int k = 0; k < 8; ++k) {
      Ao[k] = make_float4(av[4 * k] * msk, av[4 * k + 1] * msk,
                          av[4 * k + 2] * msk, av[4 * k + 3] * msk);
    }
    code_out[t] = (mk == 1) ? (float)code : 0.0f;
  }
}

// ---------------------------------------------------------------------------
// inv: quantized = A' @ C + b_inv.  C columns (e-pair) resident in registers.
// ---------------------------------------------------------------------------
__global__ __launch_bounds__(256)
void inv_kernel(const float* __restrict__ Ap, const float* __restrict__ Cw,
                const float* __restrict__ b_inv, float* __restrict__ qout) {
  const int tid = threadIdx.x;
  const int w = tid >> 6;
  const int lane = tid & 63;
  const int ep = w * 64 + lane;      // e-pair index; e = 2*ep
  const int tile = blockIdx.x * 64;
  float2 c[32];
#pragma unroll
  for (int m = 0; m < 32; ++m) c[m] = ((const float2*)(Cw + m * EMB))[ep];
  const float2 bi = ((const float2*)b_inv)[ep];
  for (int tt = 0; tt < 64; ++tt) {
    const int t = tile + tt;
    const float4* a4 = (const float4*)(Ap + (size_t)t * 32);   // uniform address
    float accx = bi.x, accy = bi.y;
#pragma unroll
    for (int k = 0; k < 8; ++k) {
      const float4 a = a4[k];
      accx += a.x * c[4 * k].x + a.y * c[4 * k + 1].x + a.z * c[4 * k + 2].x + a.w * c[4 * k + 3].x;
      accy += a.x * c[4 * k].y + a.y * c[4 * k + 1].y + a.z * c[4 * k + 2].y + a.w * c[4 * k + 3].y;
    }
    ((float2*)(qout + (size_t)t * EMB))[ep] = make_float2(accx, accy);
  }
}

// ---------------------------------------------------------------------------
extern "C" void kernel_launch(void* const* d_in, const int* in_sizes, int n_in,
                              void* d_out, int out_size, void* d_ws, size_t ws_size,
                              hipStream_t stream) {
  (void)n_in; (void)out_size; (void)ws_size;
  const float* h      = (const float*)d_in[0];
  const int*   mask   = (const int*)  d_in[1];
  const float* W_proj = (const float*)d_in[2];
  const float* b_proj = (const float*)d_in[3];
  const float* W_inv  = (const float*)d_in[4];
  const float* b_inv  = (const float*)d_in[5];
  const float* emb    = (const float*)d_in[6];

  const int N = in_sizes[1];          // 65536 tokens (32*2048)

  float* quant    = (float*)d_out;                    // [N][512]
  float* code_out = quant + (size_t)N * EMB;          // [N] as float
  float* loss_out = code_out + N;                     // [1]

  float* ws = (float*)d_ws;
  float* Ap = ws;                                     // [N][32] masked soft assign
  float* Cw = Ap + (size_t)N * MCODES;                // [32][512] = En @ W_inv
  float* G  = Cw + MCODES * EMB;                      // [32][32]  = 2*En
  float* qv = G + MCODES * VQ;                        // [32]      = ||En||^2

  prep_kernel<<<MCODES, 256, 0, stream>>>(emb, W_inv, Cw, G, qv, loss_out);
  proj_kernel<<<N / TILE, 256, 0, stream>>>(h, mask, W_proj, b_proj, G, qv, Ap, code_out);
  inv_kernel<<<N / 64, 256, 0, stream>>>(Ap, Cw, b_inv, quant);
}

// Round 34
// 103.574 us; speedup vs baseline: 1.0117x; 1.0117x over previous
//
#include <hip/hip_runtime.h>
#include <math.h>

#define EMB 512
#define VQ 32
#define MCODES 32   // 2*LOG2
#define EPS 1e-8f

#define KSTEP 32                    // e-dims per K-step
#define NSTEPS 16
#define TILE 128                    // tokens per block
#define HSTRIDE 1040                // 8 tokens * 128B + 16B pad
#define HBUFSZ (16 * HSTRIDE)       // 16640 B
#define WBUFSZ 4096                 // 32 rows * 128B
#define HOFF0 0
#define HOFF1 HBUFSZ
#define WOFF0 (2 * HBUFSZ)
#define WOFF1 (2 * HBUFSZ + WBUFSZ)
#define LDS_TOTAL (2 * HBUFSZ + 2 * WBUFSZ)   // 41472 B

#define ACC4(A, V)                                                        \
    A.x += V.x * w0.x; A.x += V.y * w1.x; A.x += V.z * w2.x; A.x += V.w * w3.x; \
    A.y += V.x * w0.y; A.y += V.y * w1.y; A.y += V.z * w2.y; A.y += V.w * w3.y; \
    A.z += V.x * w0.z; A.z += V.y * w1.z; A.z += V.z * w2.z; A.z += V.w * w3.z; \
    A.w += V.x * w0.w; A.w += V.y * w1.w; A.w += V.z * w2.w; A.w += V.w * w3.w;

// ---------------------------------------------------------------------------
// prep: normalize codebook rows, G = 2*En, q = ||En||^2, C = En @ W_inv
// ---------------------------------------------------------------------------
__global__ __launch_bounds__(256)
void prep_kernel(const float* __restrict__ emb, const float* __restrict__ W_inv,
                 float* __restrict__ Cw, float* __restrict__ G, float* __restrict__ qv,
                 float* __restrict__ loss_out) {
  const int b = blockIdx.x;
  const int tid = threadIdx.x;
  __shared__ float En_s[VQ];
  float ss = 0.f;
#pragma unroll
  for (int d = 0; d < VQ; ++d) { float v = emb[b * VQ + d]; ss += v * v; }
  const float inv = 1.0f / (sqrtf(ss) + EPS);
  if (tid < VQ) En_s[tid] = emb[b * VQ + tid] * inv;
  __syncthreads();
  float a0 = 0.f, a1 = 0.f;
#pragma unroll 8
  for (int d = 0; d < VQ; ++d) {
    const float en = En_s[d];
    const float2 wv = ((const float2*)(W_inv + d * EMB))[tid];
    a0 += en * wv.x;
    a1 += en * wv.y;
  }
  ((float2*)(Cw + b * EMB))[tid] = make_float2(a0, a1);
  if (tid < VQ) G[b * VQ + tid] = 2.0f * En_s[tid];
  if (tid == 0) {
    float qq = 0.f;
#pragma unroll
    for (int d = 0; d < VQ; ++d) qq += En_s[d] * En_s[d];
    qv[b] = qq;
    if (b == 0) loss_out[0] = 0.0f;   // vq_loss
  }
}

// ---------------------------------------------------------------------------
// proj v9 — FINAL (session-best, reproduced 9x at 104-107us total):
// async-staged 2-phase (m97 pattern). Per K-step: stage(next buf) via 5
// async 1KB gload_lds per wave issued BEFORE compute, compute current buf
// from LDS, barrier. 128 tok/block, grid 512 (2 blocks/CU -> cross-block
// stage/compute overlap). Verified absmax 9.77e-4.
// ---------------------------------------------------------------------------
__global__ __launch_bounds__(256)
void proj_kernel(const float* __restrict__ h, const int* __restrict__ mask,
                 const float* __restrict__ W_proj, const float* __restrict__ b_proj,
                 const float* __restrict__ G, const float* __restrict__ qv,
                 float* __restrict__ Aout, float* __restrict__ code_out) {
  const int tid = threadIdx.x;
  const int w = tid >> 6;            // wave 0..3
  const int lane = tid & 63;
  const int dg = tid & 7;            // out-dims 4*dg..4*dg+3
  const int ts = tid >> 3;           // 0..31 : token-strip (4 tokens)
  const int tile = blockIdx.x * TILE;

  __shared__ __align__(16) char lds[LDS_TOTAL];

  const int hoff[2] = {HOFF0, HOFF1};
  const int woff[2] = {WOFF0, WOFF1};

  const int srow = lane >> 3;        // staging: row within 8-row call
  const int scol = (lane & 7) * 4;   // staging: float offset (16B granule)

  // ---- async stage of one K-step into buffer b (issue-only, no waits) ----
  auto stage = [&](int b, int s) {
#pragma unroll
    for (int i = 0; i < 4; ++i) {
      const int c = 4 * w + i;
      const float* g = h + (size_t)(tile + 8 * c + srow) * EMB + s * KSTEP + scol;
      char* l = &lds[hoff[b] + c * HSTRIDE];
      __builtin_amdgcn_global_load_lds((const __attribute__((address_space(1))) void*)g,
                                       (__attribute__((address_space(3))) void*)l, 16, 0, 0);
    }
    {
      const float* g = W_proj + (size_t)(s * KSTEP + 8 * w + srow) * VQ + scol;
      char* l = &lds[woff[b] + w * 1024];
      __builtin_amdgcn_global_load_lds((const __attribute__((address_space(1))) void*)g,
                                       (__attribute__((address_space(3))) void*)l, 16, 0, 0);
    }
  };

  float4 a0 = make_float4(0.f, 0.f, 0.f, 0.f), a1 = a0, a2 = a0, a3 = a0;
  const int hrowbase = (ts >> 1) * HSTRIDE + (ts & 1) * 512;

  stage(0, 0);
  __syncthreads();                   // buf0 ready

  int b = 0;
  for (int s = 0; s < NSTEPS; ++s) {
    if (s + 1 < NSTEPS) stage(b ^ 1, s + 1);    // issue-early
    const char* hb = &lds[hoff[b]];
    const char* wb = &lds[woff[b]];
#pragma unroll
    for (int kf = 0; kf < 8; ++kf) {            // 4 k-dims per kf
      const float4 w0 = *(const float4*)(wb + (4 * kf + 0) * 128 + dg * 16);
      const float4 w1 = *(const float4*)(wb + (4 * kf + 1) * 128 + dg * 16);
      const float4 w2 = *(const float4*)(wb + (4 * kf + 2) * 128 + dg * 16);
      const float4 w3 = *(const float4*)(wb + (4 * kf + 3) * 128 + dg * 16);
      const float4 v0 = *(const float4*)(hb + hrowbase + 0 * 128 + kf * 16);
      const float4 v1 = *(const float4*)(hb + hrowbase + 1 * 128 + kf * 16);
      const float4 v2 = *(const float4*)(hb + hrowbase + 2 * 128 + kf * 16);
      const float4 v3 = *(const float4*)(hb + hrowbase + 3 * 128 + kf * 16);
      ACC4(a0, v0) ACC4(a1, v1) ACC4(a2, v2) ACC4(a3, v3)
    }
    __syncthreads();                 // drains staged loads; protects buffer reuse
    b ^= 1;
  }

  // ---- epilogue (R9-proven): redistribute via LDS, norm/softmax/code ----
  float* part = (float*)lds;         // reuse as [128][36] floats (18432B)
  *(float4*)&part[(4 * ts + 0) * 36 + dg * 4] = a0;
  *(float4*)&part[(4 * ts + 1) * 36 + dg * 4] = a1;
  *(float4*)&part[(4 * ts + 2) * 36 + dg * 4] = a2;
  *(float4*)&part[(4 * ts + 3) * 36 + dg * 4] = a3;
  __syncthreads();

  if (tid < 128) {
    const int t = tile + tid;
    const float4* bp4 = (const float4*)b_proj;
    float4 hp[8];
    float ssum = 0.f;
#pragma unroll
    for (int k = 0; k < 8; ++k) {
      float4 v = *(const float4*)&part[tid * 36 + k * 4];
      const float4 bb = bp4[k];
      v.x += bb.x; v.y += bb.y; v.z += bb.z; v.w += bb.w;
      hp[k] = v;
      ssum += v.x * v.x + v.y * v.y + v.z * v.z + v.w * v.w;
    }
    const float inv = 1.0f / (sqrtf(ssum) + EPS);
#pragma unroll
    for (int k = 0; k < 8; ++k) {
      hp[k].x *= inv; hp[k].y *= inv; hp[k].z *= inv; hp[k].w *= inv;
    }
    const float4* G4 = (const float4*)G;   // [32][8] float4, rows = 2*En_m
    float av[32];
    int code = 0;
#pragma unroll
    for (int g = 0; g < 16; ++g) {
      float d0 = 0.f, d1 = 0.f;
#pragma unroll
      for (int k = 0; k < 8; ++k) {
        const float4 g0 = G4[(2 * g) * 8 + k];
        const float4 g1 = G4[(2 * g + 1) * 8 + k];
        const float4 hv = hp[k];
        d0 += hv.x * g0.x + hv.y * g0.y + hv.z * g0.z + hv.w * g0.w;
        d1 += hv.x * g1.x + hv.y * g1.y + hv.z * g1.z + hv.w * g1.w;
      }
      // s_m = 2*hn.En_m - ||En_m||^2 (||hn||^2 cancels inside the pair softmax)
      const float s0 = d0 - qv[2 * g];
      const float s1 = d1 - qv[2 * g + 1];
      const float mx = fmaxf(s0, s1);
      const float e0 = expf(s0 - mx);
      const float e1 = expf(s1 - mx);
      const float rs = 1.0f / (e0 + e1);
      av[2 * g] = e0 * rs;
      av[2 * g + 1] = e1 * rs;
      code |= (e1 > e0) ? (1 << g) : 0;   // argmax, first index wins ties
    }
    const int mk = mask[t];
    const float msk = (mk == 1) ? 1.0f : 0.0f;
    float4* Ao = (float4*)(Aout + (size_t)t * MCODES);
#pragma unroll
    for (int k = 0; k < 8; ++k) {
      Ao[k] = make_float4(av[4 * k] * msk, av[4 * k + 1] * msk,
                          av[4 * k + 2] * msk, av[4 * k + 3] * msk);
    }
    code_out[t] = (mk == 1) ? (float)code : 0.0f;
  }
}

// ---------------------------------------------------------------------------
// inv: quantized = A' @ C + b_inv.  C columns (e-pair) resident in registers.
// ---------------------------------------------------------------------------
__global__ __launch_bounds__(256)
void inv_kernel(const float* __restrict__ Ap, const float* __restrict__ Cw,
                const float* __restrict__ b_inv, float* __restrict__ qout) {
  const int tid = threadIdx.x;
  const int w = tid >> 6;
  const int lane = tid & 63;
  const int ep = w * 64 + lane;      // e-pair index; e = 2*ep
  const int tile = blockIdx.x * 64;
  float2 c[32];
#pragma unroll
  for (int m = 0; m < 32; ++m) c[m] = ((const float2*)(Cw + m * EMB))[ep];
  const float2 bi = ((const float2*)b_inv)[ep];
  for (int tt = 0; tt < 64; ++tt) {
    const int t = tile + tt;
    const float4* a4 = (const float4*)(Ap + (size_t)t * 32);   // uniform address
    float accx = bi.x, accy = bi.y;
#pragma unroll
    for (int k = 0; k < 8; ++k) {
      const float4 a = a4[k];
      accx += a.x * c[4 * k].x + a.y * c[4 * k + 1].x + a.z * c[4 * k + 2].x + a.w * c[4 * k + 3].x;
      accy += a.x * c[4 * k].y + a.y * c[4 * k + 1].y + a.z * c[4 * k + 2].y + a.w * c[4 * k + 3].y;
    }
    ((float2*)(qout + (size_t)t * EMB))[ep] = make_float2(accx, accy);
  }
}

// ---------------------------------------------------------------------------
extern "C" void kernel_launch(void* const* d_in, const int* in_sizes, int n_in,
                              void* d_out, int out_size, void* d_ws, size_t ws_size,
                              hipStream_t stream) {
  (void)n_in; (void)out_size; (void)ws_size;
  const float* h      = (const float*)d_in[0];
  const int*   mask   = (const int*)  d_in[1];
  const float* W_proj = (const float*)d_in[2];
  const float* b_proj = (const float*)d_in[3];
  const float* W_inv  = (const float*)d_in[4];
  const float* b_inv  = (const float*)d_in[5];
  const float* emb    = (const float*)d_in[6];

  const int N = in_sizes[1];          // 65536 tokens (32*2048)

  float* quant    = (float*)d_out;                    // [N][512]
  float* code_out = quant + (size_t)N * EMB;          // [N] as float
  float* loss_out = code_out + N;                     // [1]

  float* ws = (float*)d_ws;
  float* Ap = ws;                                     // [N][32] masked soft assign
  float* Cw = Ap + (size_t)N * MCODES;                // [32][512] = En @ W_inv
  float* G  = Cw + MCODES * EMB;                      // [32][32]  = 2*En
  float* qv = G + MCODES * VQ;                        // [32]      = ||En||^2

  prep_kernel<<<MCODES, 256, 0, stream>>>(emb, W_inv, Cw, G, qv, loss_out);
  proj_kernel<<<N / TILE, 256, 0, stream>>>(h, mask, W_proj, b_proj, G, qv, Ap, code_out);
  inv_kernel<<<N / 64, 256, 0, stream>>>(Ap, Cw, b_inv, quant);
}

// Round 35
// 103.513 us; speedup vs baseline: 1.0123x; 1.0006x over previous
//
#include <hip/hip_runtime.h>
#include <math.h>

#define EMB 512
#define VQ 32
#define MCODES 32   // 2*LOG2
#define EPS 1e-8f

#define KSTEP 32                    // e-dims per K-step
#define NSTEPS 16
#define TILE 128                    // tokens per block
#define HSTRIDE 1040                // 8 tokens * 128B + 16B pad
#define HBUFSZ (16 * HSTRIDE)       // 16640 B
#define WBUFSZ 4096                 // 32 rows * 128B
#define HOFF0 0
#define HOFF1 HBUFSZ
#define WOFF0 (2 * HBUFSZ)
#define WOFF1 (2 * HBUFSZ + WBUFSZ)
#define LDS_TOTAL (2 * HBUFSZ + 2 * WBUFSZ)   // 41472 B

#define ACC4(A, V)                                                        \
    A.x += V.x * w0.x; A.x += V.y * w1.x; A.x += V.z * w2.x; A.x += V.w * w3.x; \
    A.y += V.x * w0.y; A.y += V.y * w1.y; A.y += V.z * w2.y; A.y += V.w * w3.y; \
    A.z += V.x * w0.z; A.z += V.y * w1.z; A.z += V.z * w2.z; A.z += V.w * w3.z; \
    A.w += V.x * w0.w; A.w += V.y * w1.w; A.w += V.z * w2.w; A.w += V.w * w3.w;

// ---------------------------------------------------------------------------
// prep: normalize codebook rows, G = 2*En, q = ||En||^2, C = En @ W_inv
// ---------------------------------------------------------------------------
__global__ __launch_bounds__(256)
void prep_kernel(const float* __restrict__ emb, const float* __restrict__ W_inv,
                 float* __restrict__ Cw, float* __restrict__ G, float* __restrict__ qv,
                 float* __restrict__ loss_out) {
  const int b = blockIdx.x;
  const int tid = threadIdx.x;
  __shared__ float En_s[VQ];
  float ss = 0.f;
#pragma unroll
  for (int d = 0; d < VQ; ++d) { float v = emb[b * VQ + d]; ss += v * v; }
  const float inv = 1.0f / (sqrtf(ss) + EPS);
  if (tid < VQ) En_s[tid] = emb[b * VQ + tid] * inv;
  __syncthreads();
  float a0 = 0.f, a1 = 0.f;
#pragma unroll 8
  for (int d = 0; d < VQ; ++d) {
    const float en = En_s[d];
    const float2 wv = ((const float2*)(W_inv + d * EMB))[tid];
    a0 += en * wv.x;
    a1 += en * wv.y;
  }
  ((float2*)(Cw + b * EMB))[tid] = make_float2(a0, a1);
  if (tid < VQ) G[b * VQ + tid] = 2.0f * En_s[tid];
  if (tid == 0) {
    float qq = 0.f;
#pragma unroll
    for (int d = 0; d < VQ; ++d) qq += En_s[d] * En_s[d];
    qv[b] = qq;
    if (b == 0) loss_out[0] = 0.0f;   // vq_loss
  }
}

// ---------------------------------------------------------------------------
// proj v9 — FINAL (session-best, reproduced 10x at 103-107us total):
// async-staged 2-phase (m97 pattern). Per K-step: stage(next buf) via 5
// async 1KB gload_lds per wave issued BEFORE compute, compute current buf
// from LDS, barrier. 128 tok/block, grid 512 (2 blocks/CU -> cross-block
// stage/compute overlap). Verified absmax 9.77e-4.
// ---------------------------------------------------------------------------
__global__ __launch_bounds__(256)
void proj_kernel(const float* __restrict__ h, const int* __restrict__ mask,
                 const float* __restrict__ W_proj, const float* __restrict__ b_proj,
                 const float* __restrict__ G, const float* __restrict__ qv,
                 float* __restrict__ Aout, float* __restrict__ code_out) {
  const int tid = threadIdx.x;
  const int w = tid >> 6;            // wave 0..3
  const int lane = tid & 63;
  const int dg = tid & 7;            // out-dims 4*dg..4*dg+3
  const int ts = tid >> 3;           // 0..31 : token-strip (4 tokens)
  const int tile = blockIdx.x * TILE;

  __shared__ __align__(16) char lds[LDS_TOTAL];

  const int hoff[2] = {HOFF0, HOFF1};
  const int woff[2] = {WOFF0, WOFF1};

  const int srow = lane >> 3;        // staging: row within 8-row call
  const int scol = (lane & 7) * 4;   // staging: float offset (16B granule)

  // ---- async stage of one K-step into buffer b (issue-only, no waits) ----
  auto stage = [&](int b, int s) {
#pragma unroll
    for (int i = 0; i < 4; ++i) {
      const int c = 4 * w + i;
      const float* g = h + (size_t)(tile + 8 * c + srow) * EMB + s * KSTEP + scol;
      char* l = &lds[hoff[b] + c * HSTRIDE];
      __builtin_amdgcn_global_load_lds((const __attribute__((address_space(1))) void*)g,
                                       (__attribute__((address_space(3))) void*)l, 16, 0, 0);
    }
    {
      const float* g = W_proj + (size_t)(s * KSTEP + 8 * w + srow) * VQ + scol;
      char* l = &lds[woff[b] + w * 1024];
      __builtin_amdgcn_global_load_lds((const __attribute__((address_space(1))) void*)g,
                                       (__attribute__((address_space(3))) void*)l, 16, 0, 0);
    }
  };

  float4 a0 = make_float4(0.f, 0.f, 0.f, 0.f), a1 = a0, a2 = a0, a3 = a0;
  const int hrowbase = (ts >> 1) * HSTRIDE + (ts & 1) * 512;

  stage(0, 0);
  __syncthreads();                   // buf0 ready

  int b = 0;
  for (int s = 0; s < NSTEPS; ++s) {
    if (s + 1 < NSTEPS) stage(b ^ 1, s + 1);    // issue-early
    const char* hb = &lds[hoff[b]];
    const char* wb = &lds[woff[b]];
#pragma unroll
    for (int kf = 0; kf < 8; ++kf) {            // 4 k-dims per kf
      const float4 w0 = *(const float4*)(wb + (4 * kf + 0) * 128 + dg * 16);
      const float4 w1 = *(const float4*)(wb + (4 * kf + 1) * 128 + dg * 16);
      const float4 w2 = *(const float4*)(wb + (4 * kf + 2) * 128 + dg * 16);
      const float4 w3 = *(const float4*)(wb + (4 * kf + 3) * 128 + dg * 16);
      const float4 v0 = *(const float4*)(hb + hrowbase + 0 * 128 + kf * 16);
      const float4 v1 = *(const float4*)(hb + hrowbase + 1 * 128 + kf * 16);
      const float4 v2 = *(const float4*)(hb + hrowbase + 2 * 128 + kf * 16);
      const float4 v3 = *(const float4*)(hb + hrowbase + 3 * 128 + kf * 16);
      ACC4(a0, v0) ACC4(a1, v1) ACC4(a2, v2) ACC4(a3, v3)
    }
    __syncthreads();                 // drains staged loads; protects buffer reuse
    b ^= 1;
  }

  // ---- epilogue (R9-proven): redistribute via LDS, norm/softmax/code ----
  float* part = (float*)lds;         // reuse as [128][36] floats (18432B)
  *(float4*)&part[(4 * ts + 0) * 36 + dg * 4] = a0;
  *(float4*)&part[(4 * ts + 1) * 36 + dg * 4] = a1;
  *(float4*)&part[(4 * ts + 2) * 36 + dg * 4] = a2;
  *(float4*)&part[(4 * ts + 3) * 36 + dg * 4] = a3;
  __syncthreads();

  if (tid < 128) {
    const int t = tile + tid;
    const float4* bp4 = (const float4*)b_proj;
    float4 hp[8];
    float ssum = 0.f;
#pragma unroll
    for (int k = 0; k < 8; ++k) {
      float4 v = *(const float4*)&part[tid * 36 + k * 4];
      const float4 bb = bp4[k];
      v.x += bb.x; v.y += bb.y; v.z += bb.z; v.w += bb.w;
      hp[k] = v;
      ssum += v.x * v.x + v.y * v.y + v.z * v.z + v.w * v.w;
    }
    const float inv = 1.0f / (sqrtf(ssum) + EPS);
#pragma unroll
    for (int k = 0; k < 8; ++k) {
      hp[k].x *= inv; hp[k].y *= inv; hp[k].z *= inv; hp[k].w *= inv;
    }
    const float4* G4 = (const float4*)G;   // [32][8] float4, rows = 2*En_m
    float av[32];
    int code = 0;
#pragma unroll
    for (int g = 0; g < 16; ++g) {
      float d0 = 0.f, d1 = 0.f;
#pragma unroll
      for (int k = 0; k < 8; ++k) {
        const float4 g0 = G4[(2 * g) * 8 + k];
        const float4 g1 = G4[(2 * g + 1) * 8 + k];
        const float4 hv = hp[k];
        d0 += hv.x * g0.x + hv.y * g0.y + hv.z * g0.z + hv.w * g0.w;
        d1 += hv.x * g1.x + hv.y * g1.y + hv.z * g1.z + hv.w * g1.w;
      }
      // s_m = 2*hn.En_m - ||En_m||^2 (||hn||^2 cancels inside the pair softmax)
      const float s0 = d0 - qv[2 * g];
      const float s1 = d1 - qv[2 * g + 1];
      const float mx = fmaxf(s0, s1);
      const float e0 = expf(s0 - mx);
      const float e1 = expf(s1 - mx);
      const float rs = 1.0f / (e0 + e1);
      av[2 * g] = e0 * rs;
      av[2 * g + 1] = e1 * rs;
      code |= (e1 > e0) ? (1 << g) : 0;   // argmax, first index wins ties
    }
    const int mk = mask[t];
    const float msk = (mk == 1) ? 1.0f : 0.0f;
    float4* Ao = (float4*)(Aout + (size_t)t * MCODES);
#pragma unroll
    for (int k = 0; k < 8; ++k) {
      Ao[k] = make_float4(av[4 * k] * msk, av[4 * k + 1] * msk,
                          av[4 * k + 2] * msk, av[4 * k + 3] * msk);
    }
    code_out[t] = (mk == 1) ? (float)code : 0.0f;
  }
}

// ---------------------------------------------------------------------------
// inv: quantized = A' @ C + b_inv.  C columns (e-pair) resident in registers.
// ---------------------------------------------------------------------------
__global__ __launch_bounds__(256)
void inv_kernel(const float* __restrict__ Ap, const float* __restrict__ Cw,
                const float* __restrict__ b_inv, float* __restrict__ qout) {
  const int tid = threadIdx.x;
  const int w = tid >> 6;
  const int lane = tid & 63;
  const int ep = w * 64 + lane;      // e-pair index; e = 2*ep
  const int tile = blockIdx.x * 64;
  float2 c[32];
#pragma unroll
  for (int m = 0; m < 32; ++m) c[m] = ((const float2*)(Cw + m * EMB))[ep];
  const float2 bi = ((const float2*)b_inv)[ep];
  for (int tt = 0; tt < 64; ++tt) {
    const int t = tile + tt;
    const float4* a4 = (const float4*)(Ap + (size_t)t * 32);   // uniform address
    float accx = bi.x, accy = bi.y;
#pragma unroll
    for (int k = 0; k < 8; ++k) {
      const float4 a = a4[k];
      accx += a.x * c[4 * k].x + a.y * c[4 * k + 1].x + a.z * c[4 * k + 2].x + a.w * c[4 * k + 3].x;
      accy += a.x * c[4 * k].y + a.y * c[4 * k + 1].y + a.z * c[4 * k + 2].y + a.w * c[4 * k + 3].y;
    }
    ((float2*)(qout + (size_t)t * EMB))[ep] = make_float2(accx, accy);
  }
}

// ---------------------------------------------------------------------------
extern "C" void kernel_launch(void* const* d_in, const int* in_sizes, int n_in,
                              void* d_out, int out_size, void* d_ws, size_t ws_size,
                              hipStream_t stream) {
  (void)n_in; (void)out_size; (void)ws_size;
  const float* h      = (const float*)d_in[0];
  const int*   mask   = (const int*)  d_in[1];
  const float* W_proj = (const float*)d_in[2];
  const float* b_proj = (const float*)d_in[3];
  const float* W_inv  = (const float*)d_in[4];
  const float* b_inv  = (const float*)d_in[5];
  const float* emb    = (const float*)d_in[6];

  const int N = in_sizes[1];          // 65536 tokens (32*2048)

  float* quant    = (float*)d_out;                    // [N][512]
  float* code_out = quant + (size_t)N * EMB;          // [N] as float
  float* loss_out = code_out + N;                     // [1]

  float* ws = (float*)d_ws;
  float* Ap = ws;                                     // [N][32] masked soft assign
  float* Cw = Ap + (size_t)N * MCODES;                // [32][512] = En @ W_inv
  float* G  = Cw + MCODES * EMB;                      // [32][32]  = 2*En
  float* qv = G + MCODES * VQ;                        // [32]      = ||En||^2

  prep_kernel<<<MCODES, 256, 0, stream>>>(emb, W_inv, Cw, G, qv, loss_out);
  proj_kernel<<<N / TILE, 256, 0, stream>>>(h, mask, W_proj, b_proj, G, qv, Ap, code_out);
  inv_kernel<<<N / 64, 256, 0, stream>>>(Ap, Cw, b_inv, quant);
}